// Round 1
// baseline (557.845 us; speedup 1.0000x reference)
//
#include <hip/hip_runtime.h>
#include <stdint.h>

// ---------------------------------------------------------------------------
// RichAttention: out = softmax(QK^T - w*cdist(coords)) @ V, attn also output.
// B=8, S=2048, H=768, fp32 in/out.
// Precision: Q/K path via split-fp16 (hi+lo, 3-term MFMA) -> ~fp32 scores.
//            V/PV path single fp16 MFMA (out threshold is 2% of maxabs~5).
// ---------------------------------------------------------------------------

typedef _Float16 half8 __attribute__((ext_vector_type(8)));
typedef _Float16 half4v __attribute__((ext_vector_type(4)));
typedef float f32x4 __attribute__((ext_vector_type(4)));

#define DEVI static __device__ __forceinline__

constexpr int B_ = 8, S_ = 2048, H_ = 768;
constexpr long NX = (long)B_ * S_ * H_;  // 12,582,912
constexpr long NW = (long)H_ * H_;       // 589,824

// ---- async global->LDS, 16B per lane --------------------------------------
DEVI void glds16(const void* g, void* l) {
  __builtin_amdgcn_global_load_lds(
      (const __attribute__((address_space(1))) uint32_t*)g,
      (__attribute__((address_space(3))) uint32_t*)l, 16, 0, 0);
}

// Stage a [128][32]-fp16 tile (8KB) from row-major global (rowStride elems).
// LDS slot (r,c) holds global chunk c ^ ((r>>1)&3)  (chunk = 16B = 8 halves).
// 256 threads, 2 units each; lds dest is wave-uniform base + lane*16B.
DEVI void stage_tile(const _Float16* gbase, int rowStride, _Float16* lds, int tid) {
#pragma unroll
  for (int seg = 0; seg < 2; ++seg) {
    int u = seg * 256 + tid;
    int r = u >> 2, c = u & 3;
    int sc = c ^ ((r >> 1) & 3);
    glds16(gbase + (long)r * rowStride + sc * 8, lds + ((u & ~63) << 3));
  }
}

// MFMA 16x16x32 A/B fragment read: lane holds [row=l&15][k=(l>>4)*8 .. +8].
DEVI half8 frag(const _Float16* lds, int m0, int lane) {
  int row = m0 + (lane & 15);
  int c = (lane >> 4) ^ ((row >> 1) & 3);
  return *(const half8*)(lds + row * 32 + c * 8);
}

// ---------------------------------------------------------------------------
// K0: split inputs (queries/keys/values) and weights into fp16 hi/lo pairs.
// Destination: d_out used as scratch (dead until K2 writes scores).
// Layout (halves): [Xq_hi][Xq_lo][Xk_hi][Xk_lo][Xv_hi][Xv_lo]  (z*2*NX, +NX)
//                  then [Wq_hi][Wq_lo][Wk_hi][Wk_lo][Wv_hi][Wv_lo] at 6*NX.
// ---------------------------------------------------------------------------
__global__ __launch_bounds__(256) void k_split(
    const float* __restrict__ xq, const float* __restrict__ xk,
    const float* __restrict__ xv, const float* __restrict__ wq,
    const float* __restrict__ wk, const float* __restrict__ wv,
    _Float16* __restrict__ dst) {
  const long NX4 = NX / 4, NW4 = NW / 4, TOT = 3 * NX4 + 3 * NW4;
  for (long u = (long)blockIdx.x * blockDim.x + threadIdx.x; u < TOT;
       u += (long)gridDim.x * blockDim.x) {
    const float4* src;
    _Float16 *dh, *dl;
    long idx;
    if (u < 3 * NX4) {
      int z = (u >= 2 * NX4) ? 2 : (u >= NX4) ? 1 : 0;
      idx = u - (long)z * NX4;
      src = (const float4*)(z == 0 ? xq : z == 1 ? xk : xv);
      dh = dst + (long)z * 2 * NX;
      dl = dh + NX;
    } else {
      long t = u - 3 * NX4;
      int z = (t >= 2 * NW4) ? 2 : (t >= NW4) ? 1 : 0;
      idx = t - (long)z * NW4;
      src = (const float4*)(z == 0 ? wq : z == 1 ? wk : wv);
      dh = dst + 6 * NX + (long)z * 2 * NW;
      dl = dh + NW;
    }
    float4 x = src[idx];
    half4v hi, lo;
    hi[0] = (_Float16)x.x; lo[0] = (_Float16)(x.x - (float)hi[0]);
    hi[1] = (_Float16)x.y; lo[1] = (_Float16)(x.y - (float)hi[1]);
    hi[2] = (_Float16)x.z; lo[2] = (_Float16)(x.z - (float)hi[2]);
    hi[3] = (_Float16)x.w; lo[3] = (_Float16)(x.w - (float)hi[3]);
    *(half4v*)(dh + idx * 4) = hi;
    *(half4v*)(dl + idx * 4) = lo;
  }
}

// ---------------------------------------------------------------------------
// K1: projections Y = X @ W^T + b. z=0: Q (store hi/lo fp16), z=1: K (hi/lo),
// z=2: V stored TRANSPOSED v_T[b][h][t] fp16 (single-term MFMA is enough).
// Tile 128x128, BK=32, 4 waves (2x2 of 64x64), double-buffered LDS.
// ---------------------------------------------------------------------------
__global__ __launch_bounds__(256, 2) void k_proj(
    const _Float16* __restrict__ scratch, const float* __restrict__ bq,
    const float* __restrict__ bk, const float* __restrict__ bv,
    _Float16* __restrict__ qh, _Float16* __restrict__ ql,
    _Float16* __restrict__ kh, _Float16* __restrict__ kl,
    _Float16* __restrict__ vT) {
  const int nt = blockIdx.x, mt = blockIdx.y, z = blockIdx.z;
  const int tid = threadIdx.x;
  const bool full = (z < 2);
  const _Float16* Xh = scratch + (long)z * 2 * NX;
  const _Float16* Xl = Xh + NX;
  const _Float16* Wh = scratch + 6 * NX + (long)z * 2 * NW;
  const _Float16* Wl = Wh + NW;
  const float* bias = (z == 0) ? bq : (z == 1) ? bk : bv;

  __shared__ _Float16 sm[2][4][4096];  // [buf][Ahi,Alo,Bhi,Blo][128*32]

  f32x4 acc[4][4] = {};

  const _Float16* Ah = Xh + (long)(mt * 128) * H_;
  const _Float16* Al = Xl + (long)(mt * 128) * H_;
  const _Float16* Bh = Wh + (long)(nt * 128) * H_;
  const _Float16* Bl = Wl + (long)(nt * 128) * H_;

  stage_tile(Ah, H_, sm[0][0], tid);
  stage_tile(Bh, H_, sm[0][2], tid);
  if (full) {
    stage_tile(Al, H_, sm[0][1], tid);
    stage_tile(Bl, H_, sm[0][3], tid);
  }
  __syncthreads();

  const int lane = tid & 63, wid = tid >> 6;
  const int wm = (wid >> 1) * 64, wn = (wid & 1) * 64;

  int cur = 0;
  for (int kk = 0; kk < 24; ++kk) {
    if (kk + 1 < 24) {
      int o = (kk + 1) * 32;
      stage_tile(Ah + o, H_, sm[cur ^ 1][0], tid);
      stage_tile(Bh + o, H_, sm[cur ^ 1][2], tid);
      if (full) {
        stage_tile(Al + o, H_, sm[cur ^ 1][1], tid);
        stage_tile(Bl + o, H_, sm[cur ^ 1][3], tid);
      }
    }
    half8 ah[4], bh[4];
#pragma unroll
    for (int i = 0; i < 4; ++i) ah[i] = frag(sm[cur][0], wm + i * 16, lane);
#pragma unroll
    for (int j = 0; j < 4; ++j) bh[j] = frag(sm[cur][2], wn + j * 16, lane);
#pragma unroll
    for (int i = 0; i < 4; ++i)
#pragma unroll
      for (int j = 0; j < 4; ++j)
        acc[i][j] = __builtin_amdgcn_mfma_f32_16x16x32_f16(ah[i], bh[j],
                                                           acc[i][j], 0, 0, 0);
    if (full) {
      half8 al[4], bl[4];
#pragma unroll
      for (int i = 0; i < 4; ++i) al[i] = frag(sm[cur][1], wm + i * 16, lane);
#pragma unroll
      for (int j = 0; j < 4; ++j) bl[j] = frag(sm[cur][3], wn + j * 16, lane);
#pragma unroll
      for (int i = 0; i < 4; ++i)
#pragma unroll
        for (int j = 0; j < 4; ++j) {
          acc[i][j] = __builtin_amdgcn_mfma_f32_16x16x32_f16(ah[i], bl[j],
                                                             acc[i][j], 0, 0, 0);
          acc[i][j] = __builtin_amdgcn_mfma_f32_16x16x32_f16(al[i], bh[j],
                                                             acc[i][j], 0, 0, 0);
        }
    }
    __syncthreads();
    cur ^= 1;
  }

  // Epilogue. C/D layout: col = lane&15, row = (lane>>4)*4 + reg.
  _Float16* oh = (z == 0) ? qh : kh;
  _Float16* ol = (z == 0) ? ql : kl;
#pragma unroll
  for (int i = 0; i < 4; ++i) {
    int m_t = wm + i * 16 + ((lane >> 4) << 2);
#pragma unroll
    for (int j = 0; j < 4; ++j) {
      int n_t = wn + j * 16 + (lane & 15);
      int gn = nt * 128 + n_t;
      float bs = bias[gn];
      if (z < 2) {
#pragma unroll
        for (int r = 0; r < 4; ++r) {
          long gm = (long)mt * 128 + m_t + r;
          float y = acc[i][j][r] + bs;
          _Float16 hi = (_Float16)y;
          oh[gm * H_ + gn] = hi;
          ol[gm * H_ + gn] = (_Float16)(y - (float)hi);
        }
      } else {
        int gmI = mt * 128 + m_t;
        int bb = gmI >> 11, t0 = gmI & 2047;
        half4v pk;
#pragma unroll
        for (int r = 0; r < 4; ++r) pk[r] = (_Float16)(acc[i][j][r] + bs);
        *(half4v*)&vT[((long)bb * H_ + gn) * S_ + t0] = pk;  // 8B contiguous
      }
    }
  }
}

// ---------------------------------------------------------------------------
// K2: raw scores = q.k (3-term split-fp16) - w*dist -> attn region (fp32).
// ---------------------------------------------------------------------------
__global__ __launch_bounds__(256, 2) void k_scores(
    const _Float16* __restrict__ qh, const _Float16* __restrict__ ql,
    const _Float16* __restrict__ kh, const _Float16* __restrict__ kl,
    const float* __restrict__ coords, const float* __restrict__ sw,
    float* __restrict__ attn) {
  const int nt = blockIdx.x, mt = blockIdx.y, b = blockIdx.z;
  const int tid = threadIdx.x;
  __shared__ _Float16 sm[2][4][4096];
  __shared__ float cr[2][128], cc[2][128];

  if (tid < 128) {
    long gi = (long)b * S_ + mt * 128 + tid;
    cr[0][tid] = coords[gi * 2 + 0];
    cr[1][tid] = coords[gi * 2 + 1];
  } else {
    int t = tid - 128;
    long gj = (long)b * S_ + nt * 128 + t;
    cc[0][t] = coords[gj * 2 + 0];
    cc[1][t] = coords[gj * 2 + 1];
  }
  const float w = sw[0];

  f32x4 acc[4][4] = {};
  const long aoff = ((long)b * S_ + mt * 128) * H_;
  const long boff = ((long)b * S_ + nt * 128) * H_;
  const _Float16* Ah = qh + aoff;
  const _Float16* Al = ql + aoff;
  const _Float16* Bh = kh + boff;
  const _Float16* Bl = kl + boff;

  stage_tile(Ah, H_, sm[0][0], tid);
  stage_tile(Al, H_, sm[0][1], tid);
  stage_tile(Bh, H_, sm[0][2], tid);
  stage_tile(Bl, H_, sm[0][3], tid);
  __syncthreads();

  const int lane = tid & 63, wid = tid >> 6;
  const int wm = (wid >> 1) * 64, wn = (wid & 1) * 64;

  int cur = 0;
  for (int kk = 0; kk < 24; ++kk) {
    if (kk + 1 < 24) {
      int o = (kk + 1) * 32;
      stage_tile(Ah + o, H_, sm[cur ^ 1][0], tid);
      stage_tile(Al + o, H_, sm[cur ^ 1][1], tid);
      stage_tile(Bh + o, H_, sm[cur ^ 1][2], tid);
      stage_tile(Bl + o, H_, sm[cur ^ 1][3], tid);
    }
    half8 ah[4], al4[4], bh[4], bl4[4];
#pragma unroll
    for (int i = 0; i < 4; ++i) {
      ah[i] = frag(sm[cur][0], wm + i * 16, lane);
      al4[i] = frag(sm[cur][1], wm + i * 16, lane);
    }
#pragma unroll
    for (int j = 0; j < 4; ++j) {
      bh[j] = frag(sm[cur][2], wn + j * 16, lane);
      bl4[j] = frag(sm[cur][3], wn + j * 16, lane);
    }
#pragma unroll
    for (int i = 0; i < 4; ++i)
#pragma unroll
      for (int j = 0; j < 4; ++j) {
        acc[i][j] = __builtin_amdgcn_mfma_f32_16x16x32_f16(ah[i], bh[j],
                                                           acc[i][j], 0, 0, 0);
        acc[i][j] = __builtin_amdgcn_mfma_f32_16x16x32_f16(ah[i], bl4[j],
                                                           acc[i][j], 0, 0, 0);
        acc[i][j] = __builtin_amdgcn_mfma_f32_16x16x32_f16(al4[i], bh[j],
                                                           acc[i][j], 0, 0, 0);
      }
    __syncthreads();
    cur ^= 1;
  }

  // Epilogue: subtract w * dist, store raw scores.
#pragma unroll
  for (int i = 0; i < 4; ++i) {
    int m_t = wm + i * 16 + ((lane >> 4) << 2);
#pragma unroll
    for (int j = 0; j < 4; ++j) {
      int n_t = wn + j * 16 + (lane & 15);
      float cjx = cc[0][n_t], cjy = cc[1][n_t];
      long rowbase = ((long)b * S_ + mt * 128 + m_t) * S_ + nt * 128 + n_t;
#pragma unroll
      for (int r = 0; r < 4; ++r) {
        float dx = cr[0][m_t + r] - cjx;
        float dy = cr[1][m_t + r] - cjy;
        float d = sqrtf(fmaxf(fmaf(dx, dx, dy * dy), 1e-12f));
        attn[rowbase + (long)r * S_] = acc[i][j][r] - w * d;
      }
    }
  }
}

// ---------------------------------------------------------------------------
// K2b: row softmax in place. One wave per row (2048 floats = 32 VGPR/lane).
// ---------------------------------------------------------------------------
__global__ __launch_bounds__(256) void k_rowsoft(float* __restrict__ attn) {
  const int wid = threadIdx.x >> 6, lane = threadIdx.x & 63;
  float* p = attn + ((long)blockIdx.x * 4 + wid) * S_;
  float4 v[8];
#pragma unroll
  for (int i = 0; i < 8; ++i) v[i] = ((const float4*)p)[i * 64 + lane];
  float m = -3.4e38f;
#pragma unroll
  for (int i = 0; i < 8; ++i)
    m = fmaxf(m, fmaxf(fmaxf(v[i].x, v[i].y), fmaxf(v[i].z, v[i].w)));
#pragma unroll
  for (int o = 32; o > 0; o >>= 1) m = fmaxf(m, __shfl_xor(m, o));
  float l = 0.f;
#pragma unroll
  for (int i = 0; i < 8; ++i) {
    v[i].x = __expf(v[i].x - m);
    v[i].y = __expf(v[i].y - m);
    v[i].z = __expf(v[i].z - m);
    v[i].w = __expf(v[i].w - m);
    l += (v[i].x + v[i].y) + (v[i].z + v[i].w);
  }
#pragma unroll
  for (int o = 32; o > 0; o >>= 1) l += __shfl_xor(l, o);
  const float rl = 1.0f / l;
#pragma unroll
  for (int i = 0; i < 8; ++i) {
    v[i].x *= rl; v[i].y *= rl; v[i].z *= rl; v[i].w *= rl;
    ((float4*)p)[i * 64 + lane] = v[i];
  }
}

// ---------------------------------------------------------------------------
// K3: out = attn @ V.  A reg-staged from fp32 attn (convert->fp16, issue-early
// write-late), B = v_T via global_load_lds. Tile 128x128, K=2048, BK=32.
// ---------------------------------------------------------------------------
__global__ __launch_bounds__(256, 2) void k_pv(
    const float* __restrict__ attn, const _Float16* __restrict__ vT,
    float* __restrict__ outp) {
  const int nt = blockIdx.x, mt = blockIdx.y, b = blockIdx.z;
  const int tid = threadIdx.x;
  __shared__ _Float16 sm[2][2][4096];  // [buf][A,B]
  f32x4 acc[4][4] = {};
  const float* Ab = attn + ((long)b * S_ + mt * 128) * S_;
  const _Float16* Bb = vT + ((long)b * H_ + nt * 128) * S_;
  const int lane = tid & 63, wid = tid >> 6;
  const int wm = (wid >> 1) * 64, wn = (wid & 1) * 64;

  stage_tile(Bb, S_, sm[0][1], tid);
#pragma unroll
  for (int seg = 0; seg < 2; ++seg) {
    int u = seg * 256 + tid, r = u >> 2, c = u & 3;
    int sc = c ^ ((r >> 1) & 3);
    const float4* s4 = (const float4*)(Ab + (long)r * S_ + sc * 8);
    float4 x0 = s4[0], x1 = s4[1];
    half8 h = {(_Float16)x0.x, (_Float16)x0.y, (_Float16)x0.z, (_Float16)x0.w,
               (_Float16)x1.x, (_Float16)x1.y, (_Float16)x1.z, (_Float16)x1.w};
    *(half8*)(&sm[0][0][r * 32 + c * 8]) = h;
  }
  __syncthreads();

  int cur = 0;
  for (int kk = 0; kk < 64; ++kk) {
    float4 x0a, x1a, x0b, x1b;
    const bool pre = (kk + 1 < 64);
    if (pre) {
      stage_tile(Bb + (kk + 1) * 32, S_, sm[cur ^ 1][1], tid);
      {
        int u = tid, r = u >> 2, sc = (u & 3) ^ ((r >> 1) & 3);
        const float4* s4 =
            (const float4*)(Ab + (long)r * S_ + (kk + 1) * 32 + sc * 8);
        x0a = s4[0]; x1a = s4[1];
      }
      {
        int u = 256 + tid, r = u >> 2, sc = (u & 3) ^ ((r >> 1) & 3);
        const float4* s4 =
            (const float4*)(Ab + (long)r * S_ + (kk + 1) * 32 + sc * 8);
        x0b = s4[0]; x1b = s4[1];
      }
    }
    half8 ah[4], bh[4];
#pragma unroll
    for (int i = 0; i < 4; ++i) ah[i] = frag(sm[cur][0], wm + i * 16, lane);
#pragma unroll
    for (int j = 0; j < 4; ++j) bh[j] = frag(sm[cur][1], wn + j * 16, lane);
#pragma unroll
    for (int i = 0; i < 4; ++i)
#pragma unroll
      for (int j = 0; j < 4; ++j)
        acc[i][j] = __builtin_amdgcn_mfma_f32_16x16x32_f16(ah[i], bh[j],
                                                           acc[i][j], 0, 0, 0);
    if (pre) {  // write-late: HBM latency hidden under the MFMAs above
      {
        int u = tid, r = u >> 2, c = u & 3;
        half8 h = {(_Float16)x0a.x, (_Float16)x0a.y, (_Float16)x0a.z,
                   (_Float16)x0a.w, (_Float16)x1a.x, (_Float16)x1a.y,
                   (_Float16)x1a.z, (_Float16)x1a.w};
        *(half8*)(&sm[cur ^ 1][0][r * 32 + c * 8]) = h;
      }
      {
        int u = 256 + tid, r = u >> 2, c = u & 3;
        half8 h = {(_Float16)x0b.x, (_Float16)x0b.y, (_Float16)x0b.z,
                   (_Float16)x0b.w, (_Float16)x1b.x, (_Float16)x1b.y,
                   (_Float16)x1b.z, (_Float16)x1b.w};
        *(half8*)(&sm[cur ^ 1][0][r * 32 + c * 8]) = h;
      }
    }
    __syncthreads();
    cur ^= 1;
  }

#pragma unroll
  for (int i = 0; i < 4; ++i) {
    int m_t = wm + i * 16 + ((lane >> 4) << 2);
#pragma unroll
    for (int j = 0; j < 4; ++j) {
      int n_t = wn + j * 16 + (lane & 15);
      int h = nt * 128 + n_t;
      long rowbase = (long)b * S_ + mt * 128 + m_t;
#pragma unroll
      for (int r = 0; r < 4; ++r) outp[(rowbase + r) * H_ + h] = acc[i][j][r];
    }
  }
}

// ---------------------------------------------------------------------------
extern "C" void kernel_launch(void* const* d_in, const int* in_sizes, int n_in,
                              void* d_out, int out_size, void* d_ws,
                              size_t ws_size, hipStream_t stream) {
  const float* xq = (const float*)d_in[0];
  const float* xk = (const float*)d_in[1];
  const float* xv = (const float*)d_in[2];
  const float* co = (const float*)d_in[3];
  const float* wq = (const float*)d_in[4];
  const float* bq = (const float*)d_in[5];
  const float* wk = (const float*)d_in[6];
  const float* bk = (const float*)d_in[7];
  const float* wv = (const float*)d_in[8];
  const float* bv = (const float*)d_in[9];
  const float* sw = (const float*)d_in[10];

  float* out = (float*)d_out;
  float* attn = out + NX;                   // attn region of d_out
  _Float16* scratch = (_Float16*)d_out;     // K0/K1 scratch (dead before K2)

  // ws: q_hi,q_lo,k_hi,k_lo (fp16 [16384][768]) + v_T (fp16 [8][768][2048])
  // total 120 MB.
  _Float16* qh = (_Float16*)d_ws;
  _Float16* ql = qh + NX;
  _Float16* kh = ql + NX;
  _Float16* kl = kh + NX;
  _Float16* vT = kl + NX;

  k_split<<<dim3(2048), 256, 0, stream>>>(xq, xk, xv, wq, wk, wv, scratch);
  k_proj<<<dim3(6, 128, 3), 256, 0, stream>>>(scratch, bq, bk, bv, qh, ql, kh,
                                              kl, vT);
  k_scores<<<dim3(16, 16, 8), 256, 0, stream>>>(qh, ql, kh, kl, co, sw, attn);
  k_rowsoft<<<dim3(4096), 256, 0, stream>>>(attn);
  k_pv<<<dim3(6, 16, 8), 256, 0, stream>>>(attn, vT, out);
}